// Round 2
// baseline (175.587 us; speedup 1.0000x reference)
//
#include <hip/hip_runtime.h>
#include <hip/hip_bf16.h>
#include <stdint.h>
#include <stddef.h>

// Problem: out[b, p*768+e] = sum_d x[b,d]*W[p,d]*GE[d,e] + bias[p]
//  == GEMM: A[r=b*256+p, d] = x[b,d]*W[p,d];  OUT = A(16384x2000) @ GE(2000x768)
// mask input is redundant (weight pre-masked at setup; mask is exact 0/1).
// Dtypes follow the fp32 reference: ALL inputs fp32, output fp32.
// (Round-1 NaN = fp32 bits read as bf16 -> random NaN patterns. Fixed.)
// Internally: A and GE^T are downconverted to bf16 in d_ws, GEMM uses
// mfma_f32_16x16x32_bf16 with fp32 accumulate. Error budget ~8e-3 vs 3.2e-2.
//
// Workspace: A (16384 x 2016 bf16 = 66,060,288 B) + GT (768 x 2016 bf16 =
// 3,096,576 B) = 69,156,864 B required in d_ws.

#define F_GENES 2000
#define KPAD    2016      // 63 * 32, zero-padded K
#define P_PATH  256
#define EMB     768
#define BATCH   64
#define M_ROWS  16384     // BATCH * P_PATH
#define KSTEPS  63

typedef __bf16 bf16x8 __attribute__((ext_vector_type(8)));
typedef float  f32x4  __attribute__((ext_vector_type(4)));

__device__ __forceinline__ unsigned short f2b(float f) {
    union { __hip_bfloat16 h; unsigned short s; } v; v.h = __float2bfloat16(f); return v.s;
}

__device__ __forceinline__ void gload16(const void* g, void* l) {
    // async global->LDS, 16B/lane; LDS dest = wave-uniform base + lane*16
    __builtin_amdgcn_global_load_lds((const __attribute__((address_space(1))) void*)g,
                                     (__attribute__((address_space(3))) void*)l,
                                     16, 0, 0);
}

// P1: A[r, 0..2015] = bf16( x[b,d] * W[p,d] ), zero-padded d in [2000,2016).
// One thread = 8 contiguous d (16B bf16 store). 252 segs/row; segs 250,251 pad.
__global__ void build_a_kernel(const float* __restrict__ x,
                               const float* __restrict__ w,
                               unsigned short* __restrict__ A) {
    int gid = blockIdx.x * 256 + threadIdx.x;          // exact: 16384*252 threads
    int r   = gid / 252;
    int s   = gid - r * 252;
    int d0  = s * 8;
    uint4 ov = make_uint4(0u, 0u, 0u, 0u);
    if (s < 250) {
        int b = r >> 8, p = r & 255;
        const float* xp = x + (size_t)b * F_GENES + d0;
        const float* wp = w + (size_t)p * F_GENES + d0;
        float4 x0 = *(const float4*)(xp);
        float4 x1 = *(const float4*)(xp + 4);
        float4 w0 = *(const float4*)(wp);
        float4 w1 = *(const float4*)(wp + 4);
        unsigned short* os = (unsigned short*)&ov;
        os[0] = f2b(x0.x * w0.x);
        os[1] = f2b(x0.y * w0.y);
        os[2] = f2b(x0.z * w0.z);
        os[3] = f2b(x0.w * w0.w);
        os[4] = f2b(x1.x * w1.x);
        os[5] = f2b(x1.y * w1.y);
        os[6] = f2b(x1.z * w1.z);
        os[7] = f2b(x1.w * w1.w);
    }
    *(uint4*)(A + (size_t)r * KPAD + d0) = ov;
}

// P2: GT[n, k] = bf16( GE[k, n] )  (N-major so GEMM B-staging is
// non-transposing), zero-padded k in [2000,2016). One thread = 8 contiguous k.
__global__ void transpose_ge_kernel(const float* __restrict__ ge,
                                    unsigned short* __restrict__ GT) {
    int gid = blockIdx.x * 256 + threadIdx.x;          // exact: 768*252 threads
    int n   = gid / 252;
    int s   = gid - n * 252;
    int k0  = s * 8;
    uint4 ov = make_uint4(0u, 0u, 0u, 0u);
    unsigned short* os = (unsigned short*)&ov;
#pragma unroll
    for (int j = 0; j < 8; ++j) {
        int k = k0 + j;
        os[j] = (k < F_GENES) ? f2b(ge[(size_t)k * EMB + n]) : (unsigned short)0;
    }
    *(uint4*)(GT + (size_t)n * KPAD + k0) = ov;
}

// GEMM: OUT(16384x768 fp32) = A(16384xKPAD bf16) @ GT^T + bias[r&255]
// m97 structure: 128x128 tile, BK=32, 4 waves in 2x2, 4x4 frags of 16x16x32,
// global_load_lds width-16 staging, 2-barrier K-loop.
__global__ __launch_bounds__(256, 3)
void gemm_kernel(const __bf16* __restrict__ A, const __bf16* __restrict__ GT,
                 const float* __restrict__ bias,
                 float* __restrict__ out) {
    __shared__ __align__(16) __bf16 As[128 * 32];   // [m][k] rows of 64B
    __shared__ __align__(16) __bf16 Bs[128 * 32];   // [n][k] rows of 64B

    const int tid  = threadIdx.x;
    const int w    = tid >> 6;
    const int l    = tid & 63;
    const int quad = l >> 4;
    const int ln   = l & 15;
    const int wr   = w >> 1;        // wave row (0..1)
    const int wc   = w & 1;         // wave col (0..1)

    const int gx = blockIdx.x;
    const int ct = gx % 6;          // col tile (768 / 128)
    const int rt = gx / 6;          // row tile (16384 / 128)

    // staging: thread t loads row (t/4), k-seg (t%4)*8; wave w deposits
    // 1024B at LDS base + w*1024 (lane order == global order -> [m][k] tile).
    const __bf16* Ag = A  + (size_t)(rt * 128 + (tid >> 2)) * KPAD + (tid & 3) * 8;
    const __bf16* Bg = GT + (size_t)(ct * 128 + (tid >> 2)) * KPAD + (tid & 3) * 8;
    __bf16* AsW = As + w * 512;     // elements (1024B per wave)
    __bf16* BsW = Bs + w * 512;

    f32x4 acc[4][4] = {};

    for (int ks = 0; ks < KSTEPS; ++ks) {
        gload16(Ag,             AsW);          // rows 0..63 of A-tile
        gload16(Ag + 64 * KPAD, AsW + 2048);   // rows 64..127
        gload16(Bg,             BsW);
        gload16(Bg + 64 * KPAD, BsW + 2048);
        Ag += 32; Bg += 32;
        __syncthreads();                       // drains vmcnt: staging visible

        bf16x8 a[4], b[4];
#pragma unroll
        for (int i = 0; i < 4; ++i)
            a[i] = *(const bf16x8*)(As + (wr * 64 + i * 16 + ln) * 32 + quad * 8);
#pragma unroll
        for (int i = 0; i < 4; ++i)
            b[i] = *(const bf16x8*)(Bs + (wc * 64 + i * 16 + ln) * 32 + quad * 8);

#pragma unroll
        for (int mi = 0; mi < 4; ++mi)
#pragma unroll
            for (int ni = 0; ni < 4; ++ni)
                acc[mi][ni] = __builtin_amdgcn_mfma_f32_16x16x32_bf16(
                    a[mi], b[ni], acc[mi][ni], 0, 0, 0);
        __syncthreads();                       // tile consumed; safe to overwrite
    }

    // epilogue: C/D layout col=ln, row=quad*4+reg (m89/m91-verified)
    const int rbase = rt * 128 + wr * 64 + quad * 4;
    const int cbase = ct * 128 + wc * 64 + ln;
#pragma unroll
    for (int mi = 0; mi < 4; ++mi) {
#pragma unroll
        for (int reg = 0; reg < 4; ++reg) {
            int r = rbase + mi * 16 + reg;
            float bv = bias[r & 255];          // p = r % 256
            size_t ro = (size_t)r * EMB;
#pragma unroll
            for (int ni = 0; ni < 4; ++ni)
                out[ro + cbase + ni * 16] = acc[mi][ni][reg] + bv;
        }
    }
}

extern "C" void kernel_launch(void* const* d_in, const int* in_sizes, int n_in,
                              void* d_out, int out_size, void* d_ws, size_t ws_size,
                              hipStream_t stream) {
    // inputs (fp32): x(64x2000), weight(256x2000), bias(256), mask(unused), ge(2000x768)
    const float* x    = (const float*)d_in[0];
    const float* wgt  = (const float*)d_in[1];
    const float* bias = (const float*)d_in[2];
    const float* ge   = (const float*)d_in[4];
    float* out = (float*)d_out;

    // workspace layout: A bf16 (16384 x 2016) | GT bf16 (768 x 2016)
    char* ws = (char*)d_ws;
    unsigned short* Abuf = (unsigned short*)ws;
    unsigned short* GTb  = (unsigned short*)(ws + (size_t)M_ROWS * KPAD * 2);

    build_a_kernel<<<(M_ROWS * 252) / 256, 256, 0, stream>>>(x, wgt, Abuf);
    transpose_ge_kernel<<<(EMB * 252) / 256, 256, 0, stream>>>(ge, GTb);
    gemm_kernel<<<(M_ROWS / 128) * (EMB / 128), 256, 0, stream>>>(
        (const __bf16*)Abuf, (const __bf16*)GTb, bias, out);
}

// Round 3
// 150.919 us; speedup vs baseline: 1.1635x; 1.1635x over previous
//
#include <hip/hip_runtime.h>
#include <hip/hip_bf16.h>
#include <stdint.h>
#include <stddef.h>

// out[b, p*768+e] = sum_d x[b,d]*W[p,d]*GE[d,e] + bias[p]
// == per-b GEMM: OUT_b(256x768) = (x_b ⊙ W)(256x2000) @ GE(2000x768) + bias
// mask input redundant (weight pre-masked; mask exact 0/1). fp32 I/O.
//
// R3 change vs R2: A (16384x2016 bf16, 66 MB) is NO LONGER materialized.
// With 128-row M-tiles, each tile spans exactly one b (b=rt>>1, p0=(rt&1)*128),
// so A_tile[m][k] = x[b,k]*W[p0+m,k] is built in-register from a staged bf16
// W-tile and a broadcast x-slice. Kills build_a (~40us), kills GEMM's 203 MB
// A-fetch (operands now L2-resident: Wb 1MB + GT 3MB + xb 256KB). Gather
// transpose replaced by LDS-tiled transpose (~9 MB coalesced traffic).
//
// Workspace: xb 64x2016 bf16 (258,048 B) | Wb 256x2016 bf16 (1,032,192 B) |
// GT 768x2016 bf16 (3,096,576 B) = 4,386,816 B total.

#define F_GENES 2000
#define KPAD    2016      // 63 * 32
#define P_PATH  256
#define EMB     768
#define BATCH   64
#define KSTEPS  63

typedef __bf16 bf16x8 __attribute__((ext_vector_type(8)));
typedef float  f32x4  __attribute__((ext_vector_type(4)));

__device__ __forceinline__ unsigned short f2b(float f) {
    union { __hip_bfloat16 h; unsigned short s; } v; v.h = __float2bfloat16(f); return v.s;
}

__device__ __forceinline__ void gload16(const void* g, void* l) {
    // async global->LDS, 16B/lane; LDS dest = wave-uniform base + lane*16
    __builtin_amdgcn_global_load_lds((const __attribute__((address_space(1))) void*)g,
                                     (__attribute__((address_space(3))) void*)l,
                                     16, 0, 0);
}

// K1: pack x (64 rows) and W (256 rows) fp32 -> bf16, K-padded to 2016 w/ zeros.
// One thread = 8 contiguous d. 252 segs/row (segs 250,251 pure pad).
__global__ void pack_xw_kernel(const float* __restrict__ x,
                               const float* __restrict__ w,
                               unsigned short* __restrict__ xb,
                               unsigned short* __restrict__ wb) {
    int gid = blockIdx.x * 256 + threadIdx.x;    // exact: (64+256)*252 = 80640
    int row = gid / 252;
    int s   = gid - row * 252;
    int d0  = s * 8;
    const float* src;
    unsigned short* dst;
    if (row < BATCH) { src = x + (size_t)row * F_GENES;           dst = xb + (size_t)row * KPAD; }
    else             { src = w + (size_t)(row - BATCH) * F_GENES; dst = wb + (size_t)(row - BATCH) * KPAD; }
    uint4 ov = make_uint4(0u, 0u, 0u, 0u);
    if (s < 250) {
        float4 v0 = *(const float4*)(src + d0);
        float4 v1 = *(const float4*)(src + d0 + 4);
        unsigned short* os = (unsigned short*)&ov;
        os[0] = f2b(v0.x); os[1] = f2b(v0.y); os[2] = f2b(v0.z); os[3] = f2b(v0.w);
        os[4] = f2b(v1.x); os[5] = f2b(v1.y); os[6] = f2b(v1.z); os[7] = f2b(v1.w);
    }
    *(uint4*)(dst + d0) = ov;
}

// K2: GT[n,k] = bf16(GE[k,n]), k-padded to 2016. LDS-tiled 16k x 64n transpose:
// coalesced float4 reads of GE rows, coalesced-ish 8B writes of GT rows.
__global__ void transpose_ge_kernel(const float* __restrict__ ge,
                                    unsigned short* __restrict__ GT) {
    __shared__ unsigned short tile[16][66];      // +2 pad vs 64 to spread banks
    int kt = blockIdx.x % 126;                   // 126 k-tiles (kt=125 pure pad)
    int nt = blockIdx.x / 126;                   // 12 n-tiles
    int k0 = kt * 16, n0 = nt * 64;
    int t  = threadIdx.x;
    {   // read phase: thread -> GE[k0 + (t>>4)][n0 + (t&15)*4 ..+3]
        int kr = t >> 4, nc = (t & 15) * 4;
        unsigned short a = 0, b = 0, c = 0, d = 0;
        if (k0 + kr < F_GENES) {
            float4 v = *(const float4*)(ge + (size_t)(k0 + kr) * EMB + n0 + nc);
            a = f2b(v.x); b = f2b(v.y); c = f2b(v.z); d = f2b(v.w);
        }
        tile[kr][nc + 0] = a; tile[kr][nc + 1] = b;
        tile[kr][nc + 2] = c; tile[kr][nc + 3] = d;
    }
    __syncthreads();
    {   // write phase: thread -> GT[n0 + (t>>2)][k0 + (t&3)*4 ..+3]
        int n = t >> 2, kc = (t & 3) * 4;
        ushort4 o;
        o.x = tile[kc + 0][n]; o.y = tile[kc + 1][n];
        o.z = tile[kc + 2][n]; o.w = tile[kc + 3][n];
        *(ushort4*)(GT + (size_t)(n0 + n) * KPAD + k0 + kc) = o;
    }
}

// GEMM (fused A): OUT(16384x768 fp32) = (x ⊙ W) @ GT^T + bias
// m97 structure: 128x128 tile, BK=32, 4 waves 2x2, 4x4 frags of 16x16x32.
// A-frags built in-register: af[j] = bf16( f32(Wfrag[j]) * f32(x[b, k0+quad*8+j]) ).
__global__ __launch_bounds__(256, 3)
void gemm_kernel(const __bf16* __restrict__ xb, const __bf16* __restrict__ Wb,
                 const __bf16* __restrict__ GT, const float* __restrict__ bias,
                 float* __restrict__ out) {
    __shared__ __align__(16) __bf16 Ws[128 * 32];   // [p-row][k] 64B rows
    __shared__ __align__(16) __bf16 Bs[128 * 32];   // [n-row][k]

    const int tid  = threadIdx.x;
    const int w    = tid >> 6;
    const int l    = tid & 63;
    const int quad = l >> 4;
    const int ln   = l & 15;
    const int wr   = w >> 1;
    const int wc   = w & 1;

    const int ct = blockIdx.x % 6;          // col tile (768/128)
    const int rt = blockIdx.x / 6;          // row tile (16384/128)
    const int b  = rt >> 1;                 // batch element (tile spans one b)
    const int p0 = (rt & 1) * 128;          // pathway base

    const __bf16* Wg = Wb + (size_t)(p0 + (tid >> 2)) * KPAD + (tid & 3) * 8;
    const __bf16* Bg = GT + (size_t)(ct * 128 + (tid >> 2)) * KPAD + (tid & 3) * 8;
    const __bf16* xg = xb + (size_t)b * KPAD + quad * 8;   // same for 16 ln-lanes (L1 bcast)
    __bf16* WsW = Ws + w * 512;
    __bf16* BsW = Bs + w * 512;

    f32x4 acc[4][4] = {};

    for (int ks = 0; ks < KSTEPS; ++ks) {
        gload16(Wg,             WsW);
        gload16(Wg + 64 * KPAD, WsW + 2048);
        gload16(Bg,             BsW);
        gload16(Bg + 64 * KPAD, BsW + 2048);
        Wg += 32; Bg += 32;

        bf16x8 xq = *(const bf16x8*)xg;      // independent of LDS; issued pre-barrier
        xg += 32;
        float xf0 = (float)xq[0], xf1 = (float)xq[1], xf2 = (float)xq[2], xf3 = (float)xq[3];
        float xf4 = (float)xq[4], xf5 = (float)xq[5], xf6 = (float)xq[6], xf7 = (float)xq[7];

        __syncthreads();                     // staging visible

        bf16x8 af[4], bfr[4];
#pragma unroll
        for (int i = 0; i < 4; ++i) {
            bf16x8 wf = *(const bf16x8*)(Ws + (wr * 64 + i * 16 + ln) * 32 + quad * 8);
            af[i][0] = (__bf16)((float)wf[0] * xf0);
            af[i][1] = (__bf16)((float)wf[1] * xf1);
            af[i][2] = (__bf16)((float)wf[2] * xf2);
            af[i][3] = (__bf16)((float)wf[3] * xf3);
            af[i][4] = (__bf16)((float)wf[4] * xf4);
            af[i][5] = (__bf16)((float)wf[5] * xf5);
            af[i][6] = (__bf16)((float)wf[6] * xf6);
            af[i][7] = (__bf16)((float)wf[7] * xf7);
        }
#pragma unroll
        for (int i = 0; i < 4; ++i)
            bfr[i] = *(const bf16x8*)(Bs + (wc * 64 + i * 16 + ln) * 32 + quad * 8);

#pragma unroll
        for (int mi = 0; mi < 4; ++mi)
#pragma unroll
            for (int ni = 0; ni < 4; ++ni)
                acc[mi][ni] = __builtin_amdgcn_mfma_f32_16x16x32_bf16(
                    af[mi], bfr[ni], acc[mi][ni], 0, 0, 0);

        __syncthreads();                     // tile consumed
    }

    // epilogue: C/D layout col=ln, row=quad*4+reg (m89/m91-verified)
    const int rbase = rt * 128 + wr * 64 + quad * 4;
    const int cbase = ct * 128 + wc * 64 + ln;
#pragma unroll
    for (int mi = 0; mi < 4; ++mi) {
#pragma unroll
        for (int reg = 0; reg < 4; ++reg) {
            int r = rbase + mi * 16 + reg;
            float bv = bias[r & 255];        // p = r % 256
            size_t ro = (size_t)r * EMB;
#pragma unroll
            for (int ni = 0; ni < 4; ++ni)
                out[ro + cbase + ni * 16] = acc[mi][ni][reg] + bv;
        }
    }
}

extern "C" void kernel_launch(void* const* d_in, const int* in_sizes, int n_in,
                              void* d_out, int out_size, void* d_ws, size_t ws_size,
                              hipStream_t stream) {
    // inputs (fp32): x(64x2000), weight(256x2000), bias(256), mask(unused), ge(2000x768)
    const float* x    = (const float*)d_in[0];
    const float* wgt  = (const float*)d_in[1];
    const float* bias = (const float*)d_in[2];
    const float* ge   = (const float*)d_in[4];
    float* out = (float*)d_out;

    char* ws = (char*)d_ws;
    unsigned short* xbuf = (unsigned short*)ws;                       // 258,048 B
    unsigned short* Wbuf = (unsigned short*)(ws + 258048);            // 1,032,192 B
    unsigned short* GTb  = (unsigned short*)(ws + 258048 + 1032192);  // 3,096,576 B

    pack_xw_kernel<<<((BATCH + P_PATH) * 252) / 256, 256, 0, stream>>>(x, wgt, xbuf, Wbuf);
    transpose_ge_kernel<<<126 * 12, 256, 0, stream>>>(ge, GTb);
    gemm_kernel<<<(16384 / 128) * (EMB / 128), 256, 0, stream>>>(
        (const __bf16*)xbuf, (const __bf16*)Wbuf, (const __bf16*)GTb, bias, out);
}

// Round 4
// 149.030 us; speedup vs baseline: 1.1782x; 1.0127x over previous
//
#include <hip/hip_runtime.h>
#include <hip/hip_bf16.h>
#include <stdint.h>
#include <stddef.h>

// out[b, p*768+e] = sum_d x[b,d]*W[p,d]*GE[d,e] + bias[p]
// == per-b GEMM: OUT_b(256x768) = (x_b ⊙ W)(256x2000) @ GE(2000x768) + bias
// mask input redundant (weight pre-masked; mask exact 0/1). fp32 I/O.
//
// R4 changes vs R3 (GEMM was barrier-bound: 3276 cyc/CU/K-step vs 930 resource
// max; MfmaUtil 24%, 6.19M LDS bank-conflict cycles):
//  1. BK=64 (KPAD 2048, 32 K-steps): halves barrier-drain events; 32 MFMA per
//     wave per phase. LDS 2x16 KB.
//  2. XOR-swizzled LDS layout: chunk' = chunk ^ (row&7), applied to the GLOBAL
//     source address per staging lane (global_load_lds dest is lane-fixed).
//     Fragment ds_read_b128: 8-lane groups hit all 32 banks -> conflict-free.
//
// Workspace: xb 64x2048 bf16 (262144 B) | Wb 256x2048 bf16 (1048576 B) |
// GT 768x2048 bf16 (3145728 B) = 4,456,448 B total.

#define F_GENES 2000
#define KPAD    2048      // 32 * 64
#define P_PATH  256
#define EMB     768
#define BATCH   64
#define KSTEPS  32        // BK = 64

typedef __bf16 bf16x8 __attribute__((ext_vector_type(8)));
typedef float  f32x4  __attribute__((ext_vector_type(4)));

__device__ __forceinline__ unsigned short f2b(float f) {
    union { __hip_bfloat16 h; unsigned short s; } v; v.h = __float2bfloat16(f); return v.s;
}

__device__ __forceinline__ void gload16(const void* g, void* l) {
    __builtin_amdgcn_global_load_lds((const __attribute__((address_space(1))) void*)g,
                                     (__attribute__((address_space(3))) void*)l,
                                     16, 0, 0);
}

// K1: pack x (64 rows) + W (256 rows) fp32 -> bf16, K-padded to 2048 w/ zeros.
// 256 segs/row (pow2); segs >= 250 are pure pad.
__global__ void pack_xw_kernel(const float* __restrict__ x,
                               const float* __restrict__ w,
                               unsigned short* __restrict__ xb,
                               unsigned short* __restrict__ wb) {
    int gid = blockIdx.x * 256 + threadIdx.x;    // (64+256)*256 = 81920 threads
    int row = gid >> 8;
    int s   = gid & 255;
    int d0  = s * 8;
    const float* src;
    unsigned short* dst;
    if (row < BATCH) { src = x + (size_t)row * F_GENES;           dst = xb + (size_t)row * KPAD; }
    else             { src = w + (size_t)(row - BATCH) * F_GENES; dst = wb + (size_t)(row - BATCH) * KPAD; }
    uint4 ov = make_uint4(0u, 0u, 0u, 0u);
    if (s < 250) {
        float4 v0 = *(const float4*)(src + d0);
        float4 v1 = *(const float4*)(src + d0 + 4);
        unsigned short* os = (unsigned short*)&ov;
        os[0] = f2b(v0.x); os[1] = f2b(v0.y); os[2] = f2b(v0.z); os[3] = f2b(v0.w);
        os[4] = f2b(v1.x); os[5] = f2b(v1.y); os[6] = f2b(v1.z); os[7] = f2b(v1.w);
    }
    *(uint4*)(dst + d0) = ov;
}

// K2: GT[n,k] = bf16(GE[k,n]), k-padded to 2048. 32k x 64n LDS tile,
// coalesced float4 reads, 16B stores (4 threads cover 64B of a GT row).
__global__ void transpose_ge_kernel(const float* __restrict__ ge,
                                    unsigned short* __restrict__ GT) {
    __shared__ unsigned short tile[64][40];      // [n][k]; stride 80B (16B-aligned rows)
    int kt = blockIdx.x & 63;                    // 64 k-tiles of 32 (kt=63 pure pad)
    int nt = blockIdx.x >> 6;                    // 12 n-tiles of 64
    int k0 = kt * 32, n0 = nt * 64;
    int t  = threadIdx.x;
    int kr = t >> 4;                             // 0..15
    int nc = (t & 15) * 4;
#pragma unroll
    for (int p = 0; p < 2; ++p) {
        int k = k0 + p * 16 + kr;
        float4 v = make_float4(0.f, 0.f, 0.f, 0.f);
        if (k < F_GENES) v = *(const float4*)(ge + (size_t)k * EMB + n0 + nc);
        int kk = p * 16 + kr;
        tile[nc + 0][kk] = f2b(v.x);
        tile[nc + 1][kk] = f2b(v.y);
        tile[nc + 2][kk] = f2b(v.z);
        tile[nc + 3][kk] = f2b(v.w);
    }
    __syncthreads();
    int n  = t >> 2;
    int kc = (t & 3) * 8;
    uint4 o;
    unsigned short* os = (unsigned short*)&o;
#pragma unroll
    for (int j = 0; j < 8; ++j) os[j] = tile[n][kc + j];
    *(uint4*)(GT + (size_t)(n0 + n) * KPAD + k0 + kc) = o;
}

// GEMM (fused A): OUT(16384x768 fp32) = (x ⊙ W) @ GT^T + bias
// 128x128 tile, BK=64, 4 waves 2x2 (wave tile 64x64), 4x4 frags 16x16x32,
// XOR-swizzled LDS, global_load_lds width-16 staging, 2-barrier K-loop.
__global__ __launch_bounds__(256, 3)
void gemm_kernel(const __bf16* __restrict__ xb, const __bf16* __restrict__ Wb,
                 const __bf16* __restrict__ GT, const float* __restrict__ bias,
                 float* __restrict__ out) {
    __shared__ __align__(16) __bf16 Ws[128 * 64];   // 16 KB, rows of 128B (8 chunks)
    __shared__ __align__(16) __bf16 Bs[128 * 64];

    const int tid  = threadIdx.x;
    const int w    = tid >> 6;
    const int l    = tid & 63;
    const int quad = l >> 4;
    const int ln   = l & 15;
    const int wr   = w >> 1;
    const int wc   = w & 1;

    const int ct = blockIdx.x % 6;          // col tile (768/128)
    const int rt = blockIdx.x / 6;          // row tile (16384/128)
    const int b  = rt >> 1;                 // batch element (tile spans one b)
    const int p0 = (rt & 1) * 128;          // pathway base

    // staging: pass p covers rows p*32..p*32+31; wave w rows w*8..w*8+7 within.
    // lane l: row sub = l>>3, chunk slot = l&7; content = global chunk (l&7)^(l>>3)
    // so LDS slot (row, c) holds global chunk c ^ (row&7)  [XOR swizzle].
    const int srow   = l >> 3;
    const int schunk = (l & 7) ^ srow;
    const __bf16* Wg = Wb + (size_t)(p0 + w * 8 + srow) * KPAD + schunk * 8;
    const __bf16* Bg = GT + (size_t)(ct * 128 + w * 8 + srow) * KPAD + schunk * 8;
    __bf16* WsW = Ws + w * 512;             // elements; + p*2048 per pass
    __bf16* BsW = Bs + w * 512;
    const __bf16* xg = xb + (size_t)b * KPAD + quad * 8;

    f32x4 acc[4][4] = {};

    for (int ks = 0; ks < KSTEPS; ++ks) {
#pragma unroll
        for (int p = 0; p < 4; ++p) {
            gload16(Wg + p * 32 * KPAD, WsW + p * 2048);
            gload16(Bg + p * 32 * KPAD, BsW + p * 2048);
        }
        Wg += 64; Bg += 64;

        bf16x8 xq0 = *(const bf16x8*)xg;         // x[b, k0 + quad*8 ..]
        bf16x8 xq1 = *(const bf16x8*)(xg + 32);  // x[b, k0+32 + quad*8 ..]
        xg += 64;

        __syncthreads();                         // staging visible

#pragma unroll
        for (int h = 0; h < 2; ++h) {
            const bf16x8 xq = h ? xq1 : xq0;
            float xf[8];
#pragma unroll
            for (int j = 0; j < 8; ++j) xf[j] = (float)xq[j];
            // chunk cc = h*4+quad; swizzled element offset within row:
            const int sw = (((h * 4 + quad) ^ (ln & 7)) * 8);

            bf16x8 af[4], bfr[4];
#pragma unroll
            for (int i = 0; i < 4; ++i) {
                bf16x8 wf = *(const bf16x8*)(Ws + (wr * 64 + i * 16 + ln) * 64 + sw);
#pragma unroll
                for (int j = 0; j < 8; ++j)
                    af[i][j] = (__bf16)((float)wf[j] * xf[j]);
            }
#pragma unroll
            for (int i = 0; i < 4; ++i)
                bfr[i] = *(const bf16x8*)(Bs + (wc * 64 + i * 16 + ln) * 64 + sw);

#pragma unroll
            for (int mi = 0; mi < 4; ++mi)
#pragma unroll
                for (int ni = 0; ni < 4; ++ni)
                    acc[mi][ni] = __builtin_amdgcn_mfma_f32_16x16x32_bf16(
                        af[mi], bfr[ni], acc[mi][ni], 0, 0, 0);
        }

        __syncthreads();                         // tile consumed
    }

    // epilogue: C/D layout col=ln, row=quad*4+reg (m89/m91-verified)
    const int rbase = rt * 128 + wr * 64 + quad * 4;
    const int cbase = ct * 128 + wc * 64 + ln;
#pragma unroll
    for (int mi = 0; mi < 4; ++mi) {
#pragma unroll
        for (int reg = 0; reg < 4; ++reg) {
            int r = rbase + mi * 16 + reg;
            float bv = bias[r & 255];            // p = r % 256
            size_t ro = (size_t)r * EMB;
#pragma unroll
            for (int ni = 0; ni < 4; ++ni)
                out[ro + cbase + ni * 16] = acc[mi][ni][reg] + bv;
        }
    }
}

extern "C" void kernel_launch(void* const* d_in, const int* in_sizes, int n_in,
                              void* d_out, int out_size, void* d_ws, size_t ws_size,
                              hipStream_t stream) {
    // inputs (fp32): x(64x2000), weight(256x2000), bias(256), mask(unused), ge(2000x768)
    const float* x    = (const float*)d_in[0];
    const float* wgt  = (const float*)d_in[1];
    const float* bias = (const float*)d_in[2];
    const float* ge   = (const float*)d_in[4];
    float* out = (float*)d_out;

    char* ws = (char*)d_ws;
    unsigned short* xbuf = (unsigned short*)ws;                        // 262144 B
    unsigned short* Wbuf = (unsigned short*)(ws + 262144);             // 1048576 B
    unsigned short* GTb  = (unsigned short*)(ws + 262144 + 1048576);   // 3145728 B

    pack_xw_kernel<<<((BATCH + P_PATH) * 256) / 256, 256, 0, stream>>>(x, wgt, xbuf, Wbuf);
    transpose_ge_kernel<<<64 * 12, 256, 0, stream>>>(ge, GTb);
    gemm_kernel<<<(16384 / 128) * (EMB / 128), 256, 0, stream>>>(
        (const __bf16*)xbuf, (const __bf16*)Wbuf, (const __bf16*)GTb, bias, out);
}

// Round 5
// 131.553 us; speedup vs baseline: 1.3347x; 1.1329x over previous
//
#include <hip/hip_runtime.h>
#include <hip/hip_bf16.h>
#include <stdint.h>
#include <stddef.h>

// out[b, p*768+e] = sum_d x[b,d]*W[p,d]*GE[d,e] + bias[p]
// == per-b GEMM: OUT_b(256x768) = (x_b ⊙ W)(256x2000) @ GE(2000x768) + bias
// mask input redundant (weight pre-masked; mask exact 0/1). fp32 I/O.
//
// R5 change vs R4 (GEMM was VALU-bound on the af build: bf16 path cost
// cvt+mul+cvt per element, VALUBusy 45% > MfmaUtil 25%): internal dtype is
// now FP16. af = wf * xq is a single v_pk_mul_f16 per 2 elements (no cvts),
// MFMA f32_16x16x32_f16 at same rate, fp32 accumulate. Precision IMPROVES
// (11-bit vs 8-bit mantissa; |x|<~5, |w|<0.022 well inside fp16 range).
//
// Workspace: xb 64x2048 f16 (262144 B) | Wb 256x2048 f16 (1048576 B) |
// GT 768x2048 f16 (3145728 B) = 4,456,448 B total.

#define F_GENES 2000
#define KPAD    2048      // 32 * 64
#define P_PATH  256
#define EMB     768
#define BATCH   64
#define KSTEPS  32        // BK = 64

typedef _Float16 f16x8 __attribute__((ext_vector_type(8)));
typedef float    f32x4 __attribute__((ext_vector_type(4)));

__device__ __forceinline__ unsigned short f2h(float f) {
    union { _Float16 h; unsigned short s; } v; v.h = (_Float16)f; return v.s;
}

__device__ __forceinline__ void gload16(const void* g, void* l) {
    __builtin_amdgcn_global_load_lds((const __attribute__((address_space(1))) void*)g,
                                     (__attribute__((address_space(3))) void*)l,
                                     16, 0, 0);
}

// K1: pack x (64 rows) + W (256 rows) fp32 -> fp16, K-padded to 2048 w/ zeros.
__global__ void pack_xw_kernel(const float* __restrict__ x,
                               const float* __restrict__ w,
                               unsigned short* __restrict__ xb,
                               unsigned short* __restrict__ wb) {
    int gid = blockIdx.x * 256 + threadIdx.x;    // (64+256)*256 = 81920 threads
    int row = gid >> 8;
    int s   = gid & 255;
    int d0  = s * 8;
    const float* src;
    unsigned short* dst;
    if (row < BATCH) { src = x + (size_t)row * F_GENES;           dst = xb + (size_t)row * KPAD; }
    else             { src = w + (size_t)(row - BATCH) * F_GENES; dst = wb + (size_t)(row - BATCH) * KPAD; }
    uint4 ov = make_uint4(0u, 0u, 0u, 0u);
    if (s < 250) {
        float4 v0 = *(const float4*)(src + d0);
        float4 v1 = *(const float4*)(src + d0 + 4);
        unsigned short* os = (unsigned short*)&ov;
        os[0] = f2h(v0.x); os[1] = f2h(v0.y); os[2] = f2h(v0.z); os[3] = f2h(v0.w);
        os[4] = f2h(v1.x); os[5] = f2h(v1.y); os[6] = f2h(v1.z); os[7] = f2h(v1.w);
    }
    *(uint4*)(dst + d0) = ov;
}

// K2: GT[n,k] = f16(GE[k,n]), k-padded to 2048. 32k x 64n LDS tile,
// coalesced float4 reads, 16B stores (4 threads cover 64B of a GT row).
__global__ void transpose_ge_kernel(const float* __restrict__ ge,
                                    unsigned short* __restrict__ GT) {
    __shared__ unsigned short tile[64][40];      // [n][k]; 16B-aligned rows
    int kt = blockIdx.x & 63;                    // 64 k-tiles of 32 (kt=63 pure pad)
    int nt = blockIdx.x >> 6;                    // 12 n-tiles of 64
    int k0 = kt * 32, n0 = nt * 64;
    int t  = threadIdx.x;
    int kr = t >> 4;                             // 0..15
    int nc = (t & 15) * 4;
#pragma unroll
    for (int p = 0; p < 2; ++p) {
        int k = k0 + p * 16 + kr;
        float4 v = make_float4(0.f, 0.f, 0.f, 0.f);
        if (k < F_GENES) v = *(const float4*)(ge + (size_t)k * EMB + n0 + nc);
        int kk = p * 16 + kr;
        tile[nc + 0][kk] = f2h(v.x);
        tile[nc + 1][kk] = f2h(v.y);
        tile[nc + 2][kk] = f2h(v.z);
        tile[nc + 3][kk] = f2h(v.w);
    }
    __syncthreads();
    int n  = t >> 2;
    int kc = (t & 3) * 8;
    uint4 o;
    unsigned short* os = (unsigned short*)&o;
#pragma unroll
    for (int j = 0; j < 8; ++j) os[j] = tile[n][kc + j];
    *(uint4*)(GT + (size_t)(n0 + n) * KPAD + k0 + kc) = o;
}

// GEMM (fused A): OUT(16384x768 fp32) = (x ⊙ W) @ GT^T + bias
// 128x128 tile, BK=64, 4 waves 2x2 (wave tile 64x64), 4x4 frags 16x16x32 f16,
// XOR-swizzled LDS (0 bank conflicts), global_load_lds width-16 staging.
__global__ __launch_bounds__(256, 3)
void gemm_kernel(const _Float16* __restrict__ xb, const _Float16* __restrict__ Wb,
                 const _Float16* __restrict__ GT, const float* __restrict__ bias,
                 float* __restrict__ out) {
    __shared__ __align__(16) _Float16 Ws[128 * 64];   // 16 KB, rows of 128B (8 chunks)
    __shared__ __align__(16) _Float16 Bs[128 * 64];

    const int tid  = threadIdx.x;
    const int w    = tid >> 6;
    const int l    = tid & 63;
    const int quad = l >> 4;
    const int ln   = l & 15;
    const int wr   = w >> 1;
    const int wc   = w & 1;

    const int ct = blockIdx.x % 6;          // col tile (768/128)
    const int rt = blockIdx.x / 6;          // row tile (16384/128)
    const int b  = rt >> 1;                 // batch element (tile spans one b)
    const int p0 = (rt & 1) * 128;          // pathway base

    // staging: pass p covers rows p*32..+31; wave w rows w*8..+7 within.
    // LDS slot (row, c) holds global chunk c ^ (row&7)  [XOR swizzle].
    const int srow   = l >> 3;
    const int schunk = (l & 7) ^ srow;
    const _Float16* Wg = Wb + (size_t)(p0 + w * 8 + srow) * KPAD + schunk * 8;
    const _Float16* Bg = GT + (size_t)(ct * 128 + w * 8 + srow) * KPAD + schunk * 8;
    _Float16* WsW = Ws + w * 512;
    _Float16* BsW = Bs + w * 512;
    const _Float16* xg = xb + (size_t)b * KPAD + quad * 8;

    f32x4 acc[4][4] = {};

    for (int ks = 0; ks < KSTEPS; ++ks) {
#pragma unroll
        for (int p = 0; p < 4; ++p) {
            gload16(Wg + p * 32 * KPAD, WsW + p * 2048);
            gload16(Bg + p * 32 * KPAD, BsW + p * 2048);
        }
        Wg += 64; Bg += 64;

        f16x8 xq0 = *(const f16x8*)xg;          // x[b, k0 + quad*8 ..]
        f16x8 xq1 = *(const f16x8*)(xg + 32);   // x[b, k0+32 + quad*8 ..]
        xg += 64;

        __syncthreads();                        // staging visible

#pragma unroll
        for (int h = 0; h < 2; ++h) {
            const f16x8 xq = h ? xq1 : xq0;
            const int sw = (((h * 4 + quad) ^ (ln & 7)) * 8);

            f16x8 af[4], bfr[4];
#pragma unroll
            for (int i = 0; i < 4; ++i) {
                f16x8 wf = *(const f16x8*)(Ws + (wr * 64 + i * 16 + ln) * 64 + sw);
                af[i] = wf * xq;                // v_pk_mul_f16 x4 — no cvts
            }
#pragma unroll
            for (int i = 0; i < 4; ++i)
                bfr[i] = *(const f16x8*)(Bs + (wc * 64 + i * 16 + ln) * 64 + sw);

#pragma unroll
            for (int mi = 0; mi < 4; ++mi)
#pragma unroll
                for (int ni = 0; ni < 4; ++ni)
                    acc[mi][ni] = __builtin_amdgcn_mfma_f32_16x16x32_f16(
                        af[mi], bfr[ni], acc[mi][ni], 0, 0, 0);
        }

        __syncthreads();                        // tile consumed
    }

    // epilogue: C/D layout col=ln, row=quad*4+reg (m89/m91-verified)
    const int rbase = rt * 128 + wr * 64 + quad * 4;
    const int cbase = ct * 128 + wc * 64 + ln;
#pragma unroll
    for (int mi = 0; mi < 4; ++mi) {
#pragma unroll
        for (int reg = 0; reg < 4; ++reg) {
            int r = rbase + mi * 16 + reg;
            float bv = bias[r & 255];           // p = r % 256
            size_t ro = (size_t)r * EMB;
#pragma unroll
            for (int ni = 0; ni < 4; ++ni)
                out[ro + cbase + ni * 16] = acc[mi][ni][reg] + bv;
        }
    }
}

extern "C" void kernel_launch(void* const* d_in, const int* in_sizes, int n_in,
                              void* d_out, int out_size, void* d_ws, size_t ws_size,
                              hipStream_t stream) {
    // inputs (fp32): x(64x2000), weight(256x2000), bias(256), mask(unused), ge(2000x768)
    const float* x    = (const float*)d_in[0];
    const float* wgt  = (const float*)d_in[1];
    const float* bias = (const float*)d_in[2];
    const float* ge   = (const float*)d_in[4];
    float* out = (float*)d_out;

    char* ws = (char*)d_ws;
    unsigned short* xbuf = (unsigned short*)ws;                        // 262144 B
    unsigned short* Wbuf = (unsigned short*)(ws + 262144);             // 1048576 B
    unsigned short* GTb  = (unsigned short*)(ws + 262144 + 1048576);   // 3145728 B

    pack_xw_kernel<<<((BATCH + P_PATH) * 256) / 256, 256, 0, stream>>>(x, wgt, xbuf, Wbuf);
    transpose_ge_kernel<<<64 * 12, 256, 0, stream>>>(ge, GTb);
    gemm_kernel<<<(16384 / 128) * (EMB / 128), 256, 0, stream>>>(
        (const _Float16*)xbuf, (const _Float16*)Wbuf, (const _Float16*)GTb, bias, out);
}